// Round 18
// baseline (95.552 us; speedup 1.0000x reference)
//
#include <hip/hip_runtime.h>
#include <hip/hip_bf16.h>

#define B_ 2
#define T_ 2048
#define C_ 1024
#define H_ 16
#define KV_ 4
#define D_ 64
#define M_ (B_*T_)   // 4096

typedef __attribute__((ext_vector_type(4))) float f32x4;
typedef __attribute__((ext_vector_type(8))) short bf16x8;

__device__ __forceinline__ float exp2fast(float x) {
  return __builtin_amdgcn_exp2f(x);   // v_exp_f32 (2^x)
}

__device__ __forceinline__ unsigned short f2bfu(float f) {
  unsigned u = __builtin_bit_cast(unsigned, f);
  u += 0x7FFFu + ((u >> 16) & 1u);   // round-to-nearest-even
  return (unsigned short)(u >> 16);
}

__device__ __forceinline__ short f2bf(float f) {
  return (short)f2bfu(f);
}

__device__ __forceinline__ float bf2f(short s) {
  unsigned u = ((unsigned)(unsigned short)s) << 16;
  return __builtin_bit_cast(float, u);
}

// packed 2xbf16 via HW instruction
__device__ __forceinline__ unsigned cvtpk(float a, float b) {
  unsigned r;
  asm("v_cvt_pk_bf16_f32 %0, %1, %2" : "=v"(r) : "v"(a), "v"(b));
  return r;
}

__device__ __forceinline__ void gld_lds16(const void* g, void* l) {
  __builtin_amdgcn_global_load_lds(
      (const __attribute__((address_space(1))) void*)g,
      (__attribute__((address_space(3))) void*)l, 16, 0, 0);
}

// ---------------- merged prep: x cast (blocks 0..4095) + W transposes ----------------
__global__ __launch_bounds__(256) void k_prep(const float* __restrict__ xin,
                                              short* __restrict__ xb,
                                              const float* __restrict__ Wq,
                                              const float* __restrict__ Wk,
                                              const float* __restrict__ Wv,
                                              const float* __restrict__ Wo,
                                              short* __restrict__ wT,
                                              short* __restrict__ woT) {
  __shared__ float tile[32][33];
  const int bid = blockIdx.x;
  const int tid = threadIdx.x;
  if (bid < 4096) {                 // ---- cast path ----
    int i = (bid * 256 + tid) * 4;
    float4 f = *(const float4*)(xin + i);
    short4 s;
    s.x = f2bf(f.x); s.y = f2bf(f.y); s.z = f2bf(f.z); s.w = f2bf(f.w);
    *(short4*)(xb + i) = s;
    return;
  }
  // ---- transpose path ----
  const int tb = bid - 4096;        // 0..2559
  const int bx = tb % 80;
  const int by = tb / 80;           // 0..31
  const int tx = tid & 31, ty = tid >> 5;
  const float* in; short* out; int Ncol, cb;
  if (bx < 32)      { in = Wq; out = wT;                       Ncol = 1024; cb = bx; }
  else if (bx < 40) { in = Wk; out = wT + (size_t)1024 * 1024; Ncol = 256;  cb = bx - 32; }
  else if (bx < 48) { in = Wv; out = wT + (size_t)1280 * 1024; Ncol = 256;  cb = bx - 40; }
  else              { in = Wo; out = woT;                      Ncol = 1024; cb = bx - 48; }
  const int R = 1024;
  int c0 = cb * 32, r0 = by * 32;
#pragma unroll
  for (int i = 0; i < 32; i += 8)
    tile[ty + i][tx] = in[(size_t)(r0 + ty + i) * Ncol + c0 + tx];
  __syncthreads();
#pragma unroll
  for (int i = 0; i < 32; i += 8)
    out[(size_t)(c0 + ty + i) * R + r0 + tx] = f2bf(tile[tx][ty + i]);
}

// ---------------- bf16 GEMM (f32 out): 64x128 tile, BK=64, 4 waves of 32x64 ----------------
__global__ __launch_bounds__(256) void k_gemm64(const short* __restrict__ A,
                                                const short* __restrict__ Bt,
                                                float* __restrict__ C,
                                                int M, int N, int K) {
  __shared__ short sA[64 * 64];
  __shared__ short sB[128 * 64];
  const int tid = threadIdx.x;
  const int wid = tid >> 6, lane = tid & 63;
  const int g = lane >> 4, c = lane & 15;
  const int wm = wid >> 1, wn = wid & 1;
  const int m0 = blockIdx.y * 64, n0 = blockIdx.x * 128;
  const int strow = tid >> 3;                      // 0..31
  const int scol  = ((tid & 7) ^ (strow & 7)) * 8; // pre-swizzled source col
  const int sw = c & 7;

  const short* Ag = A + (size_t)(m0 + strow) * K + scol;
  const short* Bg = Bt + (size_t)(n0 + strow) * K + scol;
  const int ldbase = wid * 512;

  f32x4 acc[2][4] = {};

  for (int k0 = 0; k0 < K; k0 += 64) {
#pragma unroll
    for (int i = 0; i < 2; ++i)
      gld_lds16(Ag + (size_t)(i * 32) * K + k0, &sA[i * 2048 + ldbase]);
#pragma unroll
    for (int i = 0; i < 4; ++i)
      gld_lds16(Bg + (size_t)(i * 32) * K + k0, &sB[i * 2048 + ldbase]);
    __syncthreads();
#pragma unroll
    for (int kk = 0; kk < 2; ++kk) {
      bf16x8 af[2], bfr[4];
#pragma unroll
      for (int i = 0; i < 2; ++i)
        af[i] = *(const bf16x8*)&sA[(wm * 32 + i * 16 + c) * 64 + ((kk * 4 + g) ^ sw) * 8];
#pragma unroll
      for (int j = 0; j < 4; ++j)
        bfr[j] = *(const bf16x8*)&sB[(wn * 64 + j * 16 + c) * 64 + ((kk * 4 + g) ^ sw) * 8];
#pragma unroll
      for (int i = 0; i < 2; ++i)
#pragma unroll
        for (int j = 0; j < 4; ++j)
          acc[i][j] = __builtin_amdgcn_mfma_f32_16x16x32_bf16(af[i], bfr[j], acc[i][j], 0, 0, 0);
    }
    __syncthreads();
  }
#pragma unroll
  for (int i = 0; i < 2; ++i)
#pragma unroll
    for (int j = 0; j < 4; ++j) {
      int row = m0 + wm * 32 + i * 16 + g * 4;
      int col = n0 + wn * 64 + j * 16 + c;
      float* cp = C + (size_t)row * N + col;
#pragma unroll
      for (int r = 0; r < 4; ++r) cp[(size_t)r * N] = acc[i][j][r];
    }
}

// ---------------- fused QKV GEMM: 64x128 tile; epilogue does RoPE+RMS ----------------
__global__ __launch_bounds__(256) void k_gemm_qkv(const short* __restrict__ A,
                                                  const short* __restrict__ Bt,
                                                  short* __restrict__ qkvb,
                                                  short* __restrict__ qb,
                                                  short* __restrict__ kbb,
                                                  const float* __restrict__ cosp,
                                                  const float* __restrict__ sinp) {
  __shared__ short sA[64 * 64];
  __shared__ short sB[128 * 64];
  const int N = 1536, K = 1024;
  const int tid = threadIdx.x;
  const int wid = tid >> 6, lane = tid & 63;
  const int g = lane >> 4, c = lane & 15;
  const int wm = wid >> 1, wn = wid & 1;
  const int m0 = blockIdx.y * 64, n0 = blockIdx.x * 128;
  const int strow = tid >> 3;
  const int scol  = ((tid & 7) ^ (strow & 7)) * 8;
  const int sw = c & 7;

  const short* Ag = A + (size_t)(m0 + strow) * K + scol;
  const short* Bg = Bt + (size_t)(n0 + strow) * K + scol;
  const int ldbase = wid * 512;

  f32x4 acc[2][4] = {};

  for (int k0 = 0; k0 < K; k0 += 64) {
#pragma unroll
    for (int i = 0; i < 2; ++i)
      gld_lds16(Ag + (size_t)(i * 32) * K + k0, &sA[i * 2048 + ldbase]);
#pragma unroll
    for (int i = 0; i < 4; ++i)
      gld_lds16(Bg + (size_t)(i * 32) * K + k0, &sB[i * 2048 + ldbase]);
    __syncthreads();
#pragma unroll
    for (int kk = 0; kk < 2; ++kk) {
      bf16x8 af[2], bfr[4];
#pragma unroll
      for (int i = 0; i < 2; ++i)
        af[i] = *(const bf16x8*)&sA[(wm * 32 + i * 16 + c) * 64 + ((kk * 4 + g) ^ sw) * 8];
#pragma unroll
      for (int j = 0; j < 4; ++j)
        bfr[j] = *(const bf16x8*)&sB[(wn * 64 + j * 16 + c) * 64 + ((kk * 4 + g) ^ sw) * 8];
#pragma unroll
      for (int i = 0; i < 2; ++i)
#pragma unroll
        for (int j = 0; j < 4; ++j)
          acc[i][j] = __builtin_amdgcn_mfma_f32_16x16x32_bf16(af[i], bfr[j], acc[i][j], 0, 0, 0);
    }
    __syncthreads();
  }

  const int head = blockIdx.x * 2 + wn;          // 0..23
  const int b = m0 >> 11;                        // 64-row blocks never cross batch
  const int tbase = (m0 & (T_ - 1)) + wm * 32;
  if (head < 20) {
    // RoPE + RMS on f32 accum; store pi-permuted (p = c*4 + j) b64 rows
    short* outbase = (head < 16)
        ? qb  + ((size_t)(b * H_ + head) * T_) * D_
        : kbb + ((size_t)(b * KV_ + (head - 16)) * T_) * D_;
#pragma unroll
    for (int i = 0; i < 2; ++i)
#pragma unroll
      for (int r = 0; r < 4; ++r) {
        const int t = tbase + i * 16 + g * 4 + r;
        const float ca = cosp[t * 32 + c],      sa = sinp[t * 32 + c];
        const float cbv = cosp[t * 32 + 16 + c], sbv = sinp[t * 32 + 16 + c];
        const float f0 = acc[i][0][r], f1 = acc[i][1][r];
        const float f2 = acc[i][2][r], f3 = acc[i][3][r];
        const float r0 = f0 * ca + f2 * sa;
        const float r1 = f1 * cbv + f3 * sbv;
        const float r2 = f2 * ca - f0 * sa;
        const float r3 = f3 * cbv - f1 * sbv;
        float ss = (r0 * r0 + r1 * r1) + (r2 * r2 + r3 * r3);
        ss += __shfl_xor(ss, 1);
        ss += __shfl_xor(ss, 2);
        ss += __shfl_xor(ss, 4);
        ss += __shfl_xor(ss, 8);
        const float sc = rsqrtf(ss * (1.0f / 64.0f) + 1.1920929e-07f);
        unsigned w0 = cvtpk(r0 * sc, r1 * sc);
        unsigned w1 = cvtpk(r2 * sc, r3 * sc);
        unsigned long long w = ((unsigned long long)w1 << 32) | w0;
        *(unsigned long long*)(outbase + (size_t)t * D_ + c * 4) = w;
      }
  } else {
    // raw v -> qkvb (natural layout)
#pragma unroll
    for (int i = 0; i < 2; ++i)
#pragma unroll
      for (int j = 0; j < 4; ++j) {
        int row = m0 + wm * 32 + i * 16 + g * 4;
        int col = n0 + wn * 64 + j * 16 + c;
        short* cp = qkvb + (size_t)row * N + col;
#pragma unroll
        for (int r = 0; r < 4; ++r) cp[(size_t)r * N] = f2bf(acc[i][j][r]);
      }
  }
}

// ---------------- gate + v = qkv.v + gate*ve, transposed to (B,KV,D,T) ----------------
__global__ __launch_bounds__(256) void k_vtrans(const short* __restrict__ qkvb,
                                                const float* __restrict__ ve,
                                                const float* __restrict__ x,
                                                const float* __restrict__ Wg,
                                                short* __restrict__ vT) {
  const int t0 = blockIdx.x * 64;
  const int bk = blockIdx.y;             // b*KV + kv
  const int b = bk >> 2, kv = bk & 3;
  const int tx = threadIdx.x;            // 0..63
  const int ty = threadIdx.y;            // 0..3
  __shared__ float tile[64][65];
  __shared__ float sgate[64];
  if (ty == 0) {
    const int row = b * T_ + t0 + tx;
    const float* xr = x + (size_t)row * C_;
    float a = 0.0f;
#pragma unroll 8
    for (int kk = 0; kk < 32; ++kk) a = fmaf(xr[kk], Wg[kk * KV_ + kv], a);
    sgate[tx] = 2.0f / (1.0f + __expf(-a));
  }
  __syncthreads();
#pragma unroll
  for (int i = 0; i < 16; ++i) {
    const int tr = ty + 4 * i;
    const int row = b * T_ + t0 + tr;
    float gt = sgate[tr];
    float v = bf2f(qkvb[(size_t)row * 1536 + 1280 + kv * 64 + tx]);
    v = fmaf(gt, ve[(size_t)row * (KV_ * D_) + kv * 64 + tx], v);
    tile[tr][tx] = v;
  }
  __syncthreads();
#pragma unroll
  for (int i = 0; i < 16; ++i) {
    const int d = ty + 4 * i;
    vT[((size_t)bk * 64 + d) * T_ + t0 + tx] = f2bf(tile[tx][d]);
  }
}

// ---------------- flash attention: QBLK=128, 8 waves; K dbuf, V single ----------------
// R16-proven body; sync changed to T4 counted-vmcnt + raw barriers:
// per tile each wave issues exactly 2 loads (V(kt), K(clamped kt+1));
// vmcnt(2)+bar before QK (K(kt) ready), vmcnt(1)+bar before PV (V(kt) ready),
// raw bar after PV (protects sV/sK overwrite). Prefetch stays in flight
// across barriers -- no vmcnt(0) drain in the loop.
__global__ __launch_bounds__(512) void k_attn(const short* __restrict__ qg,
                                              const short* __restrict__ kg,
                                              const short* __restrict__ vg,
                                              short* __restrict__ yb,
                                              const int* __restrict__ winp) {
  const int wsz = *winp;
  const int qt = blockIdx.x, bh = blockIdx.y;
  const int b = bh >> 4, h = bh & 15;
  const int kvh = h >> 2;
  const int tid = threadIdx.x;
  const int wid = tid >> 6, lane = tid & 63;
  const int g = lane >> 4, c = lane & 15;
  const int t0 = qt * 128 + wid * 16;

  __shared__ short sK[2][64 * 64];
  __shared__ short sV[64 * 64];
  __shared__ short spt_all[8][16][40];
  short (*spt)[40] = spt_all[wid];

  const short* qbase = qg + ((size_t)(b * H_ + h) * T_ + t0) * D_;
  const bf16x8 bq0 = *(const bf16x8*)(qbase + c * D_ + g * 8);
  const bf16x8 bq1 = *(const bf16x8*)(qbase + c * D_ + 32 + g * 8);
  const short* kbase = kg + (size_t)(b * KV_ + kvh) * T_ * D_;
  const short* vbase = vg + (size_t)(b * KV_ + kvh) * D_ * T_;

  const int srow0 = tid >> 3;
  const int sq    = ((tid & 7) ^ (srow0 & 7)) * 8;
  const int ldst0 = wid * 512;

  float m = -20000.0f, l = 0.0f;   // l = per-lane partial (reduced in epilogue)
  f32x4 o[4] = {};

  int lo = t0 - wsz + 1; if (lo < 0) lo = 0;
  const int kt_lo_w = lo >> 6;
  const int kt_hi_w = (t0 + 15) >> 6;
  int lou = qt * 128 - wsz + 1; if (lou < 0) lou = 0;
  const int kt_lo_u = lou >> 6;
  const int kt_hi_u = 2 * qt + 1;
  const int qgl = t0 + c;
  const float SC2 = 0.125f * 1.44269504088896340736f;   // scale * log2(e)

  {  // prologue: issue K(kt_lo_u); no wait (first tile's vmcnt(2) covers it)
    const short* ksrc = kbase + (size_t)(kt_lo_u * 64 + srow0) * D_ + sq;
    gld_lds16(ksrc, &sK[0][ldst0]);
  }

  int cb = 0;
  for (int kt = kt_lo_u; kt <= kt_hi_u; ++kt) {
    const int kc0 = kt * 64;
    // top staging: V(kt) into sV, K(kn) into sK[cb^1] (kn clamped: uniform count)
    {
      const short* vsrc = vbase + (size_t)srow0 * T_ + kc0 + sq;
      gld_lds16(vsrc, &sV[ldst0]);
      const int kn = (kt < kt_hi_u) ? kt + 1 : kt_hi_u;
      const short* ksrc = kbase + (size_t)(kn * 64 + srow0) * D_ + sq;
      gld_lds16(ksrc, &sK[cb ^ 1][ldst0]);
    }
    // SYNC 1: own K(kt) landed (2 newest -- V(kt), K(kn) -- may fly), then barrier
    asm volatile("s_waitcnt vmcnt(2)" ::: "memory");
    __builtin_amdgcn_s_barrier();

    const bool active = (kt >= kt_lo_w && kt <= kt_hi_w);
    unsigned pb[8];
    float fr = 1.0f;
    bool doresc = false;
    if (active) {
      // S^T = K * Q^T from sK[cb] (swizzled reads)
      f32x4 s[4] = {};
#pragma unroll
      for (int cj = 0; cj < 4; ++cj) {
        const int rbase = (cj * 16 + c) * 64;
        const int sw = (c & 7);
        bf16x8 k0 = *(const bf16x8*)&sK[cb][rbase + ((g ^ sw) * 8)];
        bf16x8 k1 = *(const bf16x8*)&sK[cb][rbase + (((4 + g) ^ sw) * 8)];
        s[cj] = __builtin_amdgcn_mfma_f32_16x16x32_bf16(k0, bq0, s[cj], 0, 0, 0);
        s[cj] = __builtin_amdgcn_mfma_f32_16x16x32_bf16(k1, bq1, s[cj], 0, 0, 0);
      }
      // softmax: sentinel mask, max reduce, defer-rescale (THR=8)
      const bool edge = (kt >= kt_hi_w) || (kt <= kt_lo_w + 1);
      float tmax = -3.0e38f;
#pragma unroll
      for (int cj = 0; cj < 4; ++cj)
#pragma unroll
        for (int r = 0; r < 4; ++r) {
          float v = s[cj][r];
          if (edge) {
            int kv = kc0 + cj * 16 + 4 * g + r;
            v = (kv <= qgl && kv > qgl - wsz) ? v : -1.0e9f;
            s[cj][r] = v;
          }
          tmax = fmaxf(tmax, v);
        }
      tmax = fmaxf(tmax, __shfl_xor(tmax, 16));
      tmax = fmaxf(tmax, __shfl_xor(tmax, 32));
      const float tms = tmax * SC2;
      doresc = !__all(tms <= m + 8.0f);
      if (doresc) {
        const float nm = fmaxf(m, tms);
        fr = exp2fast(m - nm);
        m = nm;
        l *= fr;                       // partial-l rescale (fr uniform per q-row)
      }
      const float negm = -m;
      float psum = 0.0f;
#pragma unroll
      for (int cj = 0; cj < 4; ++cj) {
        float p0 = exp2fast(fmaf(s[cj][0], SC2, negm));
        float p1 = exp2fast(fmaf(s[cj][1], SC2, negm));
        float p2 = exp2fast(fmaf(s[cj][2], SC2, negm));
        float p3 = exp2fast(fmaf(s[cj][3], SC2, negm));
        psum += (p0 + p1) + (p2 + p3);
        pb[2 * cj]     = cvtpk(p0, p1);
        pb[2 * cj + 1] = cvtpk(p2, p3);
      }
      l += psum;                       // cross-lane reduce deferred to epilogue
    }
    // SYNC 2: own V(kt) landed (only K(kn) may fly), then barrier
    asm volatile("s_waitcnt vmcnt(1)" ::: "memory");
    __builtin_amdgcn_s_barrier();

    if (active) {
      // ---- ks-phase 0: kv 0..31 ----
      {
        unsigned long long w0 = ((unsigned long long)pb[1] << 32) | pb[0];
        unsigned long long w1 = ((unsigned long long)pb[3] << 32) | pb[2];
        *(unsigned long long*)&spt[c][4 * g]      = w0;
        *(unsigned long long*)&spt[c][16 + 4 * g] = w1;
      }
      if (doresc) {   // O-rescale covers the P-write latency
#pragma unroll
        for (int nd = 0; nd < 4; ++nd)
#pragma unroll
          for (int r = 0; r < 4; ++r) o[nd][r] *= fr;
      }
      asm volatile("s_waitcnt lgkmcnt(0)" ::: "memory");
      bf16x8 bp0 = *(const bf16x8*)&spt[c][8 * g];
#pragma unroll
      for (int nd = 0; nd < 4; ++nd) {
        const int rbase = (nd * 16 + c) * 64;
        bf16x8 bv = *(const bf16x8*)&sV[rbase + ((g ^ (c & 7)) * 8)];
        o[nd] = __builtin_amdgcn_mfma_f32_16x16x32_bf16(bv, bp0, o[nd], 0, 0, 0);
      }
      // ---- ks-phase 1: kv 32..63 (same spt region; fences order read/write) ----
      asm volatile("s_waitcnt lgkmcnt(0)" ::: "memory");
      {
        unsigned long long w0 = ((unsigned long long)pb[5] << 32) | pb[4];
        unsigned long long w1 = ((unsigned long long)pb[7] << 32) | pb[6];
        *(unsigned long long*)&spt[c][4 * g]      = w0;
        *(unsigned long long*)&spt[c][16 + 4 * g] = w1;
      }
      asm volatile("s_waitcnt lgkmcnt(0)" ::: "memory");
      bf16x8 bp1 = *(const bf16x8*)&spt[c][8 * g];
#pragma unroll
      for (int nd = 0; nd < 4; ++nd) {
        const int rbase = (nd * 16 + c) * 64;
        bf16x8 bv = *(const bf16x8*)&sV[rbase + (((4 + g) ^ (c & 7)) * 8)];
        o[nd] = __builtin_amdgcn_mfma_f32_16x16x32_bf16(bv, bp1, o[nd], 0, 0, 0);
      }
    }
    // SYNC 3: execution-only barrier -- PV reads done before next tile's staging
    asm volatile("s_waitcnt lgkmcnt(0)" ::: "memory");
    __builtin_amdgcn_s_barrier();
    cb ^= 1;
  }
  // epilogue: deferred l reduction, then O^T store
  l += __shfl_xor(l, 16);
  l += __shfl_xor(l, 32);
  const float inv = 1.0f / l;
#pragma unroll
  for (int nd = 0; nd < 4; ++nd) {
    unsigned d0 = cvtpk(o[nd][0] * inv, o[nd][1] * inv);
    unsigned d1 = cvtpk(o[nd][2] * inv, o[nd][3] * inv);
    unsigned long long w = ((unsigned long long)d1 << 32) | d0;
    *(unsigned long long*)(yb + ((size_t)b * T_ + t0 + c) * C_ + h * D_ + nd * 16 + 4 * g) = w;
  }
}

extern "C" void kernel_launch(void* const* d_in, const int* in_sizes, int n_in,
                              void* d_out, int out_size, void* d_ws, size_t ws_size,
                              hipStream_t stream) {
  const float* x    = (const float*)d_in[0];
  const float* ve   = (const float*)d_in[1];
  const float* cosp = (const float*)d_in[2];
  const float* sinp = (const float*)d_in[3];
  const float* Wq   = (const float*)d_in[4];
  const float* Wk   = (const float*)d_in[5];
  const float* Wv   = (const float*)d_in[6];
  const float* Wo   = (const float*)d_in[7];
  const float* Wg   = (const float*)d_in[8];
  const int*   winp = (const int*)d_in[9];
  float* out = (float*)d_out;
  char* ws = (char*)d_ws;

  const size_t MB = 1024 * 1024;
  short* xb    = (short*)(ws);              // 8 MiB : x bf16 (4096x1024)
  short* wT    = (short*)(ws + 8  * MB);    // 3 MiB : [Wq|Wk|Wv]^T bf16
  short* woT   = (short*)(ws + 11 * MB);    // 2 MiB : Wo^T bf16
  short* qkvb  = (short*)(ws + 13 * MB);    // 12 MiB: qkv bf16 (v region used)
  short* qb    = (short*)(ws + 25 * MB);    // 8 MiB : q bf16 (B,H,T,D) pi-layout
  short* kbuf  = (short*)(ws + 33 * MB);    // 2 MiB : k bf16 (B,KV,T,D) pi-layout
  short* vT    = (short*)(ws + 35 * MB);    // 2 MiB : v bf16 (B,KV,D,T)
  short* yb    = (short*)(ws + 37 * MB);    // 8 MiB : attn out bf16 (B,T,C)

  k_prep<<<6656, 256, 0, stream>>>(x, xb, Wq, Wk, Wv, Wo, wT, woT);
  k_gemm_qkv<<<dim3(12, 64), 256, 0, stream>>>(xb, wT, qkvb, qb, kbuf, cosp, sinp);
  k_vtrans<<<dim3(32, 8), dim3(64, 4), 0, stream>>>(qkvb, ve, x, Wg, vT);
  k_attn<<<dim3(16, 32), 512, 0, stream>>>(qb, kbuf, vT, yb, winp);
  k_gemm64<<<dim3(8, 64), 256, 0, stream>>>(yb, woT, out, M_, 1024, 1024);
}

// Round 20
// 92.441 us; speedup vs baseline: 1.0337x; 1.0337x over previous
//
#include <hip/hip_runtime.h>
#include <hip/hip_bf16.h>

#define B_ 2
#define T_ 2048
#define C_ 1024
#define H_ 16
#define KV_ 4
#define D_ 64
#define M_ (B_*T_)   // 4096

typedef __attribute__((ext_vector_type(4))) float f32x4;
typedef __attribute__((ext_vector_type(8))) short bf16x8;

__device__ __forceinline__ float exp2fast(float x) {
  return __builtin_amdgcn_exp2f(x);   // v_exp_f32 (2^x)
}

__device__ __forceinline__ unsigned short f2bfu(float f) {
  unsigned u = __builtin_bit_cast(unsigned, f);
  u += 0x7FFFu + ((u >> 16) & 1u);   // round-to-nearest-even
  return (unsigned short)(u >> 16);
}

__device__ __forceinline__ short f2bf(float f) {
  return (short)f2bfu(f);
}

__device__ __forceinline__ float bf2f(short s) {
  unsigned u = ((unsigned)(unsigned short)s) << 16;
  return __builtin_bit_cast(float, u);
}

// packed 2xbf16 via HW instruction
__device__ __forceinline__ unsigned cvtpk(float a, float b) {
  unsigned r;
  asm("v_cvt_pk_bf16_f32 %0, %1, %2" : "=v"(r) : "v"(a), "v"(b));
  return r;
}

__device__ __forceinline__ void gld_lds16(const void* g, void* l) {
  __builtin_amdgcn_global_load_lds(
      (const __attribute__((address_space(1))) void*)g,
      (__attribute__((address_space(3))) void*)l, 16, 0, 0);
}

// ---------------- merged prep: x cast (blocks 0..4095) + W transposes ----------------
__global__ __launch_bounds__(256) void k_prep(const float* __restrict__ xin,
                                              short* __restrict__ xb,
                                              const float* __restrict__ Wq,
                                              const float* __restrict__ Wk,
                                              const float* __restrict__ Wv,
                                              const float* __restrict__ Wo,
                                              short* __restrict__ wT,
                                              short* __restrict__ woT) {
  __shared__ float tile[32][33];
  const int bid = blockIdx.x;
  const int tid = threadIdx.x;
  if (bid < 4096) {                 // ---- cast path ----
    int i = (bid * 256 + tid) * 4;
    float4 f = *(const float4*)(xin + i);
    short4 s;
    s.x = f2bf(f.x); s.y = f2bf(f.y); s.z = f2bf(f.z); s.w = f2bf(f.w);
    *(short4*)(xb + i) = s;
    return;
  }
  // ---- transpose path ----
  const int tb = bid - 4096;        // 0..2559
  const int bx = tb % 80;
  const int by = tb / 80;           // 0..31
  const int tx = tid & 31, ty = tid >> 5;
  const float* in; short* out; int Ncol, cb;
  if (bx < 32)      { in = Wq; out = wT;                       Ncol = 1024; cb = bx; }
  else if (bx < 40) { in = Wk; out = wT + (size_t)1024 * 1024; Ncol = 256;  cb = bx - 32; }
  else if (bx < 48) { in = Wv; out = wT + (size_t)1280 * 1024; Ncol = 256;  cb = bx - 40; }
  else              { in = Wo; out = woT;                      Ncol = 1024; cb = bx - 48; }
  const int R = 1024;
  int c0 = cb * 32, r0 = by * 32;
#pragma unroll
  for (int i = 0; i < 32; i += 8)
    tile[ty + i][tx] = in[(size_t)(r0 + ty + i) * Ncol + c0 + tx];
  __syncthreads();
#pragma unroll
  for (int i = 0; i < 32; i += 8)
    out[(size_t)(c0 + ty + i) * R + r0 + tx] = f2bf(tile[tx][ty + i]);
}

// ---------------- bf16 GEMM (f32 out): 64x128 tile, BK=64, 4 waves of 32x64 ----------------
__global__ __launch_bounds__(256) void k_gemm64(const short* __restrict__ A,
                                                const short* __restrict__ Bt,
                                                float* __restrict__ C,
                                                int M, int N, int K) {
  __shared__ short sA[64 * 64];
  __shared__ short sB[128 * 64];
  const int tid = threadIdx.x;
  const int wid = tid >> 6, lane = tid & 63;
  const int g = lane >> 4, c = lane & 15;
  const int wm = wid >> 1, wn = wid & 1;
  const int m0 = blockIdx.y * 64, n0 = blockIdx.x * 128;
  const int strow = tid >> 3;                      // 0..31
  const int scol  = ((tid & 7) ^ (strow & 7)) * 8; // pre-swizzled source col
  const int sw = c & 7;

  const short* Ag = A + (size_t)(m0 + strow) * K + scol;
  const short* Bg = Bt + (size_t)(n0 + strow) * K + scol;
  const int ldbase = wid * 512;

  f32x4 acc[2][4] = {};

  for (int k0 = 0; k0 < K; k0 += 64) {
#pragma unroll
    for (int i = 0; i < 2; ++i)
      gld_lds16(Ag + (size_t)(i * 32) * K + k0, &sA[i * 2048 + ldbase]);
#pragma unroll
    for (int i = 0; i < 4; ++i)
      gld_lds16(Bg + (size_t)(i * 32) * K + k0, &sB[i * 2048 + ldbase]);
    __syncthreads();
#pragma unroll
    for (int kk = 0; kk < 2; ++kk) {
      bf16x8 af[2], bfr[4];
#pragma unroll
      for (int i = 0; i < 2; ++i)
        af[i] = *(const bf16x8*)&sA[(wm * 32 + i * 16 + c) * 64 + ((kk * 4 + g) ^ sw) * 8];
#pragma unroll
      for (int j = 0; j < 4; ++j)
        bfr[j] = *(const bf16x8*)&sB[(wn * 64 + j * 16 + c) * 64 + ((kk * 4 + g) ^ sw) * 8];
#pragma unroll
      for (int i = 0; i < 2; ++i)
#pragma unroll
        for (int j = 0; j < 4; ++j)
          acc[i][j] = __builtin_amdgcn_mfma_f32_16x16x32_bf16(af[i], bfr[j], acc[i][j], 0, 0, 0);
    }
    __syncthreads();
  }
#pragma unroll
  for (int i = 0; i < 2; ++i)
#pragma unroll
    for (int j = 0; j < 4; ++j) {
      int row = m0 + wm * 32 + i * 16 + g * 4;
      int col = n0 + wn * 64 + j * 16 + c;
      float* cp = C + (size_t)row * N + col;
#pragma unroll
      for (int r = 0; r < 4; ++r) cp[(size_t)r * N] = acc[i][j][r];
    }
}

// ---------------- fused QKV GEMM: 64x128 tile; epilogue does RoPE+RMS ----------------
__global__ __launch_bounds__(256) void k_gemm_qkv(const short* __restrict__ A,
                                                  const short* __restrict__ Bt,
                                                  short* __restrict__ qkvb,
                                                  short* __restrict__ qb,
                                                  short* __restrict__ kbb,
                                                  const float* __restrict__ cosp,
                                                  const float* __restrict__ sinp) {
  __shared__ short sA[64 * 64];
  __shared__ short sB[128 * 64];
  const int N = 1536, K = 1024;
  const int tid = threadIdx.x;
  const int wid = tid >> 6, lane = tid & 63;
  const int g = lane >> 4, c = lane & 15;
  const int wm = wid >> 1, wn = wid & 1;
  const int m0 = blockIdx.y * 64, n0 = blockIdx.x * 128;
  const int strow = tid >> 3;
  const int scol  = ((tid & 7) ^ (strow & 7)) * 8;
  const int sw = c & 7;

  const short* Ag = A + (size_t)(m0 + strow) * K + scol;
  const short* Bg = Bt + (size_t)(n0 + strow) * K + scol;
  const int ldbase = wid * 512;

  f32x4 acc[2][4] = {};

  for (int k0 = 0; k0 < K; k0 += 64) {
#pragma unroll
    for (int i = 0; i < 2; ++i)
      gld_lds16(Ag + (size_t)(i * 32) * K + k0, &sA[i * 2048 + ldbase]);
#pragma unroll
    for (int i = 0; i < 4; ++i)
      gld_lds16(Bg + (size_t)(i * 32) * K + k0, &sB[i * 2048 + ldbase]);
    __syncthreads();
#pragma unroll
    for (int kk = 0; kk < 2; ++kk) {
      bf16x8 af[2], bfr[4];
#pragma unroll
      for (int i = 0; i < 2; ++i)
        af[i] = *(const bf16x8*)&sA[(wm * 32 + i * 16 + c) * 64 + ((kk * 4 + g) ^ sw) * 8];
#pragma unroll
      for (int j = 0; j < 4; ++j)
        bfr[j] = *(const bf16x8*)&sB[(wn * 64 + j * 16 + c) * 64 + ((kk * 4 + g) ^ sw) * 8];
#pragma unroll
      for (int i = 0; i < 2; ++i)
#pragma unroll
        for (int j = 0; j < 4; ++j)
          acc[i][j] = __builtin_amdgcn_mfma_f32_16x16x32_bf16(af[i], bfr[j], acc[i][j], 0, 0, 0);
    }
    __syncthreads();
  }

  const int head = blockIdx.x * 2 + wn;          // 0..23
  const int b = m0 >> 11;                        // 64-row blocks never cross batch
  const int tbase = (m0 & (T_ - 1)) + wm * 32;
  if (head < 20) {
    // RoPE + RMS on f32 accum; store pi-permuted (p = c*4 + j) b64 rows
    short* outbase = (head < 16)
        ? qb  + ((size_t)(b * H_ + head) * T_) * D_
        : kbb + ((size_t)(b * KV_ + (head - 16)) * T_) * D_;
#pragma unroll
    for (int i = 0; i < 2; ++i)
#pragma unroll
      for (int r = 0; r < 4; ++r) {
        const int t = tbase + i * 16 + g * 4 + r;
        const float ca = cosp[t * 32 + c],      sa = sinp[t * 32 + c];
        const float cbv = cosp[t * 32 + 16 + c], sbv = sinp[t * 32 + 16 + c];
        const float f0 = acc[i][0][r], f1 = acc[i][1][r];
        const float f2 = acc[i][2][r], f3 = acc[i][3][r];
        const float r0 = f0 * ca + f2 * sa;
        const float r1 = f1 * cbv + f3 * sbv;
        const float r2 = f2 * ca - f0 * sa;
        const float r3 = f3 * cbv - f1 * sbv;
        float ss = (r0 * r0 + r1 * r1) + (r2 * r2 + r3 * r3);
        ss += __shfl_xor(ss, 1);
        ss += __shfl_xor(ss, 2);
        ss += __shfl_xor(ss, 4);
        ss += __shfl_xor(ss, 8);
        const float sc = rsqrtf(ss * (1.0f / 64.0f) + 1.1920929e-07f);
        unsigned w0 = cvtpk(r0 * sc, r1 * sc);
        unsigned w1 = cvtpk(r2 * sc, r3 * sc);
        unsigned long long w = ((unsigned long long)w1 << 32) | w0;
        *(unsigned long long*)(outbase + (size_t)t * D_ + c * 4) = w;
      }
  } else {
    // raw v -> qkvb (natural layout)
#pragma unroll
    for (int i = 0; i < 2; ++i)
#pragma unroll
      for (int j = 0; j < 4; ++j) {
        int row = m0 + wm * 32 + i * 16 + g * 4;
        int col = n0 + wn * 64 + j * 16 + c;
        short* cp = qkvb + (size_t)row * N + col;
#pragma unroll
        for (int r = 0; r < 4; ++r) cp[(size_t)r * N] = f2bf(acc[i][j][r]);
      }
  }
}

// ---------------- gate + v = qkv.v + gate*ve, transposed to (B,KV,D,T) ----------------
__global__ __launch_bounds__(256) void k_vtrans(const short* __restrict__ qkvb,
                                                const float* __restrict__ ve,
                                                const float* __restrict__ x,
                                                const float* __restrict__ Wg,
                                                short* __restrict__ vT) {
  const int t0 = blockIdx.x * 64;
  const int bk = blockIdx.y;             // b*KV + kv
  const int b = bk >> 2, kv = bk & 3;
  const int tx = threadIdx.x;            // 0..63
  const int ty = threadIdx.y;            // 0..3
  __shared__ float tile[64][65];
  __shared__ float sgate[64];
  if (ty == 0) {
    const int row = b * T_ + t0 + tx;
    const float* xr = x + (size_t)row * C_;
    float a = 0.0f;
#pragma unroll 8
    for (int kk = 0; kk < 32; ++kk) a = fmaf(xr[kk], Wg[kk * KV_ + kv], a);
    sgate[tx] = 2.0f / (1.0f + __expf(-a));
  }
  __syncthreads();
#pragma unroll
  for (int i = 0; i < 16; ++i) {
    const int tr = ty + 4 * i;
    const int row = b * T_ + t0 + tr;
    float gt = sgate[tr];
    float v = bf2f(qkvb[(size_t)row * 1536 + 1280 + kv * 64 + tx]);
    v = fmaf(gt, ve[(size_t)row * (KV_ * D_) + kv * 64 + tx], v);
    tile[tr][tx] = v;
  }
  __syncthreads();
#pragma unroll
  for (int i = 0; i < 16; ++i) {
    const int d = ty + 4 * i;
    vT[((size_t)bk * 64 + d) * T_ + t0 + tx] = f2bf(tile[tx][d]);
  }
}

// ---------------- flash attention: QBLK=128, 8 waves; K dbuf, V single ----------------
// R13-proven body/sync (2 drain barriers/tile, two-phase spt[16][40],
// deferred-l, defer-rescale); plain __launch_bounds__(512) -- no spill.
// LDS 34816 B. Proven best: 44.0 us (R16).
__global__ __launch_bounds__(512) void k_attn(const short* __restrict__ qg,
                                              const short* __restrict__ kg,
                                              const short* __restrict__ vg,
                                              short* __restrict__ yb,
                                              const int* __restrict__ winp) {
  const int wsz = *winp;
  const int qt = blockIdx.x, bh = blockIdx.y;
  const int b = bh >> 4, h = bh & 15;
  const int kvh = h >> 2;
  const int tid = threadIdx.x;
  const int wid = tid >> 6, lane = tid & 63;
  const int g = lane >> 4, c = lane & 15;
  const int t0 = qt * 128 + wid * 16;

  __shared__ short sK[2][64 * 64];
  __shared__ short sV[64 * 64];
  __shared__ short spt_all[8][16][40];
  short (*spt)[40] = spt_all[wid];

  const short* qbase = qg + ((size_t)(b * H_ + h) * T_ + t0) * D_;
  const bf16x8 bq0 = *(const bf16x8*)(qbase + c * D_ + g * 8);
  const bf16x8 bq1 = *(const bf16x8*)(qbase + c * D_ + 32 + g * 8);
  const short* kbase = kg + (size_t)(b * KV_ + kvh) * T_ * D_;
  const short* vbase = vg + (size_t)(b * KV_ + kvh) * D_ * T_;

  const int srow0 = tid >> 3;
  const int sq    = ((tid & 7) ^ (srow0 & 7)) * 8;
  const int ldst0 = wid * 512;

  float m = -20000.0f, l = 0.0f;   // l = per-lane partial (reduced in epilogue)
  f32x4 o[4] = {};

  int lo = t0 - wsz + 1; if (lo < 0) lo = 0;
  const int kt_lo_w = lo >> 6;
  const int kt_hi_w = (t0 + 15) >> 6;
  int lou = qt * 128 - wsz + 1; if (lou < 0) lou = 0;
  const int kt_lo_u = lou >> 6;
  const int kt_hi_u = 2 * qt + 1;
  const int qgl = t0 + c;
  const float SC2 = 0.125f * 1.44269504088896340736f;   // scale * log2(e)

  {  // prologue: K tile only (V staged at loop top)
    const short* ksrc = kbase + (size_t)(kt_lo_u * 64 + srow0) * D_ + sq;
    gld_lds16(ksrc, &sK[0][ldst0]);
  }
  __syncthreads();

  int cb = 0;
  for (int kt = kt_lo_u; kt <= kt_hi_u; ++kt) {
    const int kc0 = kt * 64;
    // top staging: V(kt) into sV, K(kt+1) into sK[cb^1]
    {
      const short* vsrc = vbase + (size_t)srow0 * T_ + kc0 + sq;
      gld_lds16(vsrc, &sV[ldst0]);
    }
    if (kt < kt_hi_u) {
      const short* ksrc = kbase + (size_t)((kt + 1) * 64 + srow0) * D_ + sq;
      gld_lds16(ksrc, &sK[cb ^ 1][ldst0]);
    }
    const bool active = (kt >= kt_lo_w && kt <= kt_hi_w);
    unsigned pb[8];
    float fr = 1.0f;
    bool doresc = false;
    if (active) {
      // S^T = K * Q^T from sK[cb] (swizzled reads)
      f32x4 s[4] = {};
#pragma unroll
      for (int cj = 0; cj < 4; ++cj) {
        const int rbase = (cj * 16 + c) * 64;
        const int sw = (c & 7);
        bf16x8 k0 = *(const bf16x8*)&sK[cb][rbase + ((g ^ sw) * 8)];
        bf16x8 k1 = *(const bf16x8*)&sK[cb][rbase + (((4 + g) ^ sw) * 8)];
        s[cj] = __builtin_amdgcn_mfma_f32_16x16x32_bf16(k0, bq0, s[cj], 0, 0, 0);
        s[cj] = __builtin_amdgcn_mfma_f32_16x16x32_bf16(k1, bq1, s[cj], 0, 0, 0);
      }
      // softmax: sentinel mask, max reduce, defer-rescale (THR=8)
      const bool edge = (kt >= kt_hi_w) || (kt <= kt_lo_w + 1);
      float tmax = -3.0e38f;
#pragma unroll
      for (int cj = 0; cj < 4; ++cj)
#pragma unroll
        for (int r = 0; r < 4; ++r) {
          float v = s[cj][r];
          if (edge) {
            int kv = kc0 + cj * 16 + 4 * g + r;
            v = (kv <= qgl && kv > qgl - wsz) ? v : -1.0e9f;
            s[cj][r] = v;
          }
          tmax = fmaxf(tmax, v);
        }
      tmax = fmaxf(tmax, __shfl_xor(tmax, 16));
      tmax = fmaxf(tmax, __shfl_xor(tmax, 32));
      const float tms = tmax * SC2;
      doresc = !__all(tms <= m + 8.0f);
      if (doresc) {
        const float nm = fmaxf(m, tms);
        fr = exp2fast(m - nm);
        m = nm;
        l *= fr;                       // partial-l rescale (fr uniform per q-row)
      }
      const float negm = -m;
      float psum = 0.0f;
#pragma unroll
      for (int cj = 0; cj < 4; ++cj) {
        float p0 = exp2fast(fmaf(s[cj][0], SC2, negm));
        float p1 = exp2fast(fmaf(s[cj][1], SC2, negm));
        float p2 = exp2fast(fmaf(s[cj][2], SC2, negm));
        float p3 = exp2fast(fmaf(s[cj][3], SC2, negm));
        psum += (p0 + p1) + (p2 + p3);
        pb[2 * cj]     = cvtpk(p0, p1);
        pb[2 * cj + 1] = cvtpk(p2, p3);
      }
      l += psum;                       // cross-lane reduce deferred to epilogue
    }
    __syncthreads();   // BARRIER A: drains V(kt) + K(kt+1); all waves done with sK[cb]
    if (active) {
      // ---- ks-phase 0: kv 0..31 ----
      {
        unsigned long long w0 = ((unsigned long long)pb[1] << 32) | pb[0];
        unsigned long long w1 = ((unsigned long long)pb[3] << 32) | pb[2];
        *(unsigned long long*)&spt[c][4 * g]      = w0;
        *(unsigned long long*)&spt[c][16 + 4 * g] = w1;
      }
      if (doresc) {   // O-rescale covers the P-write latency
#pragma unroll
        for (int nd = 0; nd < 4; ++nd)
#pragma unroll
          for (int r = 0; r < 4; ++r) o[nd][r] *= fr;
      }
      asm volatile("s_waitcnt lgkmcnt(0)" ::: "memory");
      bf16x8 bp0 = *(const bf16x8*)&spt[c][8 * g];
#pragma unroll
      for (int nd = 0; nd < 4; ++nd) {
        const int rbase = (nd * 16 + c) * 64;
        bf16x8 bv = *(const bf16x8*)&sV[rbase + ((g ^ (c & 7)) * 8)];
        o[nd] = __builtin_amdgcn_mfma_f32_16x16x32_bf16(bv, bp0, o[nd], 0, 0, 0);
      }
      // ---- ks-phase 1: kv 32..63 (same spt region; fences order read/write) ----
      asm volatile("s_waitcnt lgkmcnt(0)" ::: "memory");
      {
        unsigned long long w0 = ((unsigned long long)pb[5] << 32) | pb[4];
        unsigned long long w1 = ((unsigned long long)pb[7] << 32) | pb[6];
        *(unsigned long long*)&spt[c][4 * g]      = w0;
        *(unsigned long long*)&spt[c][16 + 4 * g] = w1;
      }
      asm volatile("s_waitcnt lgkmcnt(0)" ::: "memory");
      bf16x8 bp1 = *(const bf16x8*)&spt[c][8 * g];
#pragma unroll
      for (int nd = 0; nd < 4; ++nd) {
        const int rbase = (nd * 16 + c) * 64;
        bf16x8 bv = *(const bf16x8*)&sV[rbase + (((4 + g) ^ (c & 7)) * 8)];
        o[nd] = __builtin_amdgcn_mfma_f32_16x16x32_bf16(bv, bp1, o[nd], 0, 0, 0);
      }
    }
    __syncthreads();   // BARRIER B: protect sV and sK[cb] before next tile's staging
    cb ^= 1;
  }
  // epilogue: deferred l reduction, then O^T store
  l += __shfl_xor(l, 16);
  l += __shfl_xor(l, 32);
  const float inv = 1.0f / l;
#pragma unroll
  for (int nd = 0; nd < 4; ++nd) {
    unsigned d0 = cvtpk(o[nd][0] * inv, o[nd][1] * inv);
    unsigned d1 = cvtpk(o[nd][2] * inv, o[nd][3] * inv);
    unsigned long long w = ((unsigned long long)d1 << 32) | d0;
    *(unsigned long long*)(yb + ((size_t)b * T_ + t0 + c) * C_ + h * D_ + nd * 16 + 4 * g) = w;
  }
}

extern "C" void kernel_launch(void* const* d_in, const int* in_sizes, int n_in,
                              void* d_out, int out_size, void* d_ws, size_t ws_size,
                              hipStream_t stream) {
  const float* x    = (const float*)d_in[0];
  const float* ve   = (const float*)d_in[1];
  const float* cosp = (const float*)d_in[2];
  const float* sinp = (const float*)d_in[3];
  const float* Wq   = (const float*)d_in[4];
  const float* Wk   = (const float*)d_in[5];
  const float* Wv   = (const float*)d_in[6];
  const float* Wo   = (const float*)d_in[7];
  const float* Wg   = (const float*)d_in[8];
  const int*   winp = (const int*)d_in[9];
  float* out = (float*)d_out;
  char* ws = (char*)d_ws;

  const size_t MB = 1024 * 1024;
  short* xb    = (short*)(ws);              // 8 MiB : x bf16 (4096x1024)
  short* wT    = (short*)(ws + 8  * MB);    // 3 MiB : [Wq|Wk|Wv]^T bf16
  short* woT   = (short*)(ws + 11 * MB);    // 2 MiB : Wo^T bf16
  short* qkvb  = (short*)(ws + 13 * MB);    // 12 MiB: qkv bf16 (v region used)
  short* qb    = (short*)(ws + 25 * MB);    // 8 MiB : q bf16 (B,H,T,D) pi-layout
  short* kbuf  = (short*)(ws + 33 * MB);    // 2 MiB : k bf16 (B,KV,T,D) pi-layout
  short* vT    = (short*)(ws + 35 * MB);    // 2 MiB : v bf16 (B,KV,D,T)
  short* yb    = (short*)(ws + 37 * MB);    // 8 MiB : attn out bf16 (B,T,C)

  k_prep<<<6656, 256, 0, stream>>>(x, xb, Wq, Wk, Wv, Wo, wT, woT);
  k_gemm_qkv<<<dim3(12, 64), 256, 0, stream>>>(xb, wT, qkvb, qb, kbuf, cosp, sinp);
  k_vtrans<<<dim3(32, 8), dim3(64, 4), 0, stream>>>(qkvb, ve, x, Wg, vT);
  k_attn<<<dim3(16, 32), 512, 0, stream>>>(qb, kbuf, vT, yb, winp);
  k_gemm64<<<dim3(8, 64), 256, 0, stream>>>(yb, woT, out, M_, 1024, 1024);
}

// Round 21
// 91.345 us; speedup vs baseline: 1.0461x; 1.0120x over previous
//
#include <hip/hip_runtime.h>
#include <hip/hip_bf16.h>

#define B_ 2
#define T_ 2048
#define C_ 1024
#define H_ 16
#define KV_ 4
#define D_ 64
#define M_ (B_*T_)   // 4096

typedef __attribute__((ext_vector_type(4))) float f32x4;
typedef __attribute__((ext_vector_type(8))) short bf16x8;

__device__ __forceinline__ float exp2fast(float x) {
  return __builtin_amdgcn_exp2f(x);   // v_exp_f32 (2^x)
}

__device__ __forceinline__ unsigned short f2bfu(float f) {
  unsigned u = __builtin_bit_cast(unsigned, f);
  u += 0x7FFFu + ((u >> 16) & 1u);   // round-to-nearest-even
  return (unsigned short)(u >> 16);
}

__device__ __forceinline__ short f2bf(float f) {
  return (short)f2bfu(f);
}

__device__ __forceinline__ float bf2f(short s) {
  unsigned u = ((unsigned)(unsigned short)s) << 16;
  return __builtin_bit_cast(float, u);
}

// packed 2xbf16 via HW instruction
__device__ __forceinline__ unsigned cvtpk(float a, float b) {
  unsigned r;
  asm("v_cvt_pk_bf16_f32 %0, %1, %2" : "=v"(r) : "v"(a), "v"(b));
  return r;
}

__device__ __forceinline__ void gld_lds16(const void* g, void* l) {
  __builtin_amdgcn_global_load_lds(
      (const __attribute__((address_space(1))) void*)g,
      (__attribute__((address_space(3))) void*)l, 16, 0, 0);
}

// ---------------- merged prep: x cast (blocks 0..4095) + W transposes ----------------
__global__ __launch_bounds__(256) void k_prep(const float* __restrict__ xin,
                                              short* __restrict__ xb,
                                              const float* __restrict__ Wq,
                                              const float* __restrict__ Wk,
                                              const float* __restrict__ Wv,
                                              const float* __restrict__ Wo,
                                              short* __restrict__ wT,
                                              short* __restrict__ woT) {
  __shared__ float tile[32][33];
  const int bid = blockIdx.x;
  const int tid = threadIdx.x;
  if (bid < 4096) {                 // ---- cast path ----
    int i = (bid * 256 + tid) * 4;
    float4 f = *(const float4*)(xin + i);
    short4 s;
    s.x = f2bf(f.x); s.y = f2bf(f.y); s.z = f2bf(f.z); s.w = f2bf(f.w);
    *(short4*)(xb + i) = s;
    return;
  }
  // ---- transpose path ----
  const int tb = bid - 4096;        // 0..2559
  const int bx = tb % 80;
  const int by = tb / 80;           // 0..31
  const int tx = tid & 31, ty = tid >> 5;
  const float* in; short* out; int Ncol, cb;
  if (bx < 32)      { in = Wq; out = wT;                       Ncol = 1024; cb = bx; }
  else if (bx < 40) { in = Wk; out = wT + (size_t)1024 * 1024; Ncol = 256;  cb = bx - 32; }
  else if (bx < 48) { in = Wv; out = wT + (size_t)1280 * 1024; Ncol = 256;  cb = bx - 40; }
  else              { in = Wo; out = woT;                      Ncol = 1024; cb = bx - 48; }
  const int R = 1024;
  int c0 = cb * 32, r0 = by * 32;
#pragma unroll
  for (int i = 0; i < 32; i += 8)
    tile[ty + i][tx] = in[(size_t)(r0 + ty + i) * Ncol + c0 + tx];
  __syncthreads();
#pragma unroll
  for (int i = 0; i < 32; i += 8)
    out[(size_t)(c0 + ty + i) * R + r0 + tx] = f2bf(tile[tx][ty + i]);
}

// ---------------- bf16 GEMM (f32 out): 64x128 tile, BK=128, 4 waves of 32x64 ----------------
// 16-chunk/row XOR swizzle (source chunk ^= row&15; read (kk*4+g)^c). 8 barriers/K-loop.
__global__ __launch_bounds__(256) void k_gemm64(const short* __restrict__ A,
                                                const short* __restrict__ Bt,
                                                float* __restrict__ C,
                                                int M, int N, int K) {
  __shared__ short sA[64 * 128];
  __shared__ short sB[128 * 128];
  const int tid = threadIdx.x;
  const int wid = tid >> 6, lane = tid & 63;
  const int g = lane >> 4, c = lane & 15;
  const int wm = wid >> 1, wn = wid & 1;
  const int m0 = blockIdx.y * 64, n0 = blockIdx.x * 128;
  const int strow = tid >> 4;                       // 0..15 (row within 16-row issue)
  const int scol  = ((tid & 15) ^ strow) * 8;       // pre-swizzled source chunk

  const short* Ag = A + (size_t)(m0 + strow) * K + scol;
  const short* Bg = Bt + (size_t)(n0 + strow) * K + scol;
  const int ldbase = wid * 512;

  f32x4 acc[2][4] = {};

  for (int k0 = 0; k0 < K; k0 += 128) {
#pragma unroll
    for (int i = 0; i < 4; ++i)
      gld_lds16(Ag + (size_t)(i * 16) * K + k0, &sA[i * 2048 + ldbase]);
#pragma unroll
    for (int i = 0; i < 8; ++i)
      gld_lds16(Bg + (size_t)(i * 16) * K + k0, &sB[i * 2048 + ldbase]);
    __syncthreads();
#pragma unroll
    for (int kk = 0; kk < 4; ++kk) {
      bf16x8 af[2], bfr[4];
#pragma unroll
      for (int i = 0; i < 2; ++i)
        af[i] = *(const bf16x8*)&sA[(wm * 32 + i * 16 + c) * 128 + ((kk * 4 + g) ^ c) * 8];
#pragma unroll
      for (int j = 0; j < 4; ++j)
        bfr[j] = *(const bf16x8*)&sB[(wn * 64 + j * 16 + c) * 128 + ((kk * 4 + g) ^ c) * 8];
#pragma unroll
      for (int i = 0; i < 2; ++i)
#pragma unroll
        for (int j = 0; j < 4; ++j)
          acc[i][j] = __builtin_amdgcn_mfma_f32_16x16x32_bf16(af[i], bfr[j], acc[i][j], 0, 0, 0);
    }
    __syncthreads();
  }
#pragma unroll
  for (int i = 0; i < 2; ++i)
#pragma unroll
    for (int j = 0; j < 4; ++j) {
      int row = m0 + wm * 32 + i * 16 + g * 4;
      int col = n0 + wn * 64 + j * 16 + c;
      float* cp = C + (size_t)row * N + col;
#pragma unroll
      for (int r = 0; r < 4; ++r) cp[(size_t)r * N] = acc[i][j][r];
    }
}

// ---------------- fused QKV GEMM: 64x128 tile, BK=128; epilogue does RoPE+RMS ----------------
__global__ __launch_bounds__(256) void k_gemm_qkv(const short* __restrict__ A,
                                                  const short* __restrict__ Bt,
                                                  short* __restrict__ qkvb,
                                                  short* __restrict__ qb,
                                                  short* __restrict__ kbb,
                                                  const float* __restrict__ cosp,
                                                  const float* __restrict__ sinp) {
  __shared__ short sA[64 * 128];
  __shared__ short sB[128 * 128];
  const int N = 1536, K = 1024;
  const int tid = threadIdx.x;
  const int wid = tid >> 6, lane = tid & 63;
  const int g = lane >> 4, c = lane & 15;
  const int wm = wid >> 1, wn = wid & 1;
  const int m0 = blockIdx.y * 64, n0 = blockIdx.x * 128;
  const int strow = tid >> 4;
  const int scol  = ((tid & 15) ^ strow) * 8;

  const short* Ag = A + (size_t)(m0 + strow) * K + scol;
  const short* Bg = Bt + (size_t)(n0 + strow) * K + scol;
  const int ldbase = wid * 512;

  f32x4 acc[2][4] = {};

  for (int k0 = 0; k0 < K; k0 += 128) {
#pragma unroll
    for (int i = 0; i < 4; ++i)
      gld_lds16(Ag + (size_t)(i * 16) * K + k0, &sA[i * 2048 + ldbase]);
#pragma unroll
    for (int i = 0; i < 8; ++i)
      gld_lds16(Bg + (size_t)(i * 16) * K + k0, &sB[i * 2048 + ldbase]);
    __syncthreads();
#pragma unroll
    for (int kk = 0; kk < 4; ++kk) {
      bf16x8 af[2], bfr[4];
#pragma unroll
      for (int i = 0; i < 2; ++i)
        af[i] = *(const bf16x8*)&sA[(wm * 32 + i * 16 + c) * 128 + ((kk * 4 + g) ^ c) * 8];
#pragma unroll
      for (int j = 0; j < 4; ++j)
        bfr[j] = *(const bf16x8*)&sB[(wn * 64 + j * 16 + c) * 128 + ((kk * 4 + g) ^ c) * 8];
#pragma unroll
      for (int i = 0; i < 2; ++i)
#pragma unroll
        for (int j = 0; j < 4; ++j)
          acc[i][j] = __builtin_amdgcn_mfma_f32_16x16x32_bf16(af[i], bfr[j], acc[i][j], 0, 0, 0);
    }
    __syncthreads();
  }

  const int head = blockIdx.x * 2 + wn;          // 0..23
  const int b = m0 >> 11;                        // 64-row blocks never cross batch
  const int tbase = (m0 & (T_ - 1)) + wm * 32;
  if (head < 20) {
    // RoPE + RMS on f32 accum; store pi-permuted (p = c*4 + j) b64 rows
    short* outbase = (head < 16)
        ? qb  + ((size_t)(b * H_ + head) * T_) * D_
        : kbb + ((size_t)(b * KV_ + (head - 16)) * T_) * D_;
#pragma unroll
    for (int i = 0; i < 2; ++i)
#pragma unroll
      for (int r = 0; r < 4; ++r) {
        const int t = tbase + i * 16 + g * 4 + r;
        const float ca = cosp[t * 32 + c],      sa = sinp[t * 32 + c];
        const float cbv = cosp[t * 32 + 16 + c], sbv = sinp[t * 32 + 16 + c];
        const float f0 = acc[i][0][r], f1 = acc[i][1][r];
        const float f2 = acc[i][2][r], f3 = acc[i][3][r];
        const float r0 = f0 * ca + f2 * sa;
        const float r1 = f1 * cbv + f3 * sbv;
        const float r2 = f2 * ca - f0 * sa;
        const float r3 = f3 * cbv - f1 * sbv;
        float ss = (r0 * r0 + r1 * r1) + (r2 * r2 + r3 * r3);
        ss += __shfl_xor(ss, 1);
        ss += __shfl_xor(ss, 2);
        ss += __shfl_xor(ss, 4);
        ss += __shfl_xor(ss, 8);
        const float sc = rsqrtf(ss * (1.0f / 64.0f) + 1.1920929e-07f);
        unsigned w0 = cvtpk(r0 * sc, r1 * sc);
        unsigned w1 = cvtpk(r2 * sc, r3 * sc);
        unsigned long long w = ((unsigned long long)w1 << 32) | w0;
        *(unsigned long long*)(outbase + (size_t)t * D_ + c * 4) = w;
      }
  } else {
    // raw v -> qkvb (natural layout)
#pragma unroll
    for (int i = 0; i < 2; ++i)
#pragma unroll
      for (int j = 0; j < 4; ++j) {
        int row = m0 + wm * 32 + i * 16 + g * 4;
        int col = n0 + wn * 64 + j * 16 + c;
        short* cp = qkvb + (size_t)row * N + col;
#pragma unroll
        for (int r = 0; r < 4; ++r) cp[(size_t)r * N] = f2bf(acc[i][j][r]);
      }
  }
}

// ---------------- gate + v = qkv.v + gate*ve, transposed to (B,KV,D,T) ----------------
__global__ __launch_bounds__(256) void k_vtrans(const short* __restrict__ qkvb,
                                                const float* __restrict__ ve,
                                                const float* __restrict__ x,
                                                const float* __restrict__ Wg,
                                                short* __restrict__ vT) {
  const int t0 = blockIdx.x * 64;
  const int bk = blockIdx.y;             // b*KV + kv
  const int b = bk >> 2, kv = bk & 3;
  const int tx = threadIdx.x;            // 0..63
  const int ty = threadIdx.y;            // 0..3
  __shared__ float tile[64][65];
  __shared__ float sgate[64];
  if (ty == 0) {
    const int row = b * T_ + t0 + tx;
    const float* xr = x + (size_t)row * C_;
    float a = 0.0f;
#pragma unroll 8
    for (int kk = 0; kk < 32; ++kk) a = fmaf(xr[kk], Wg[kk * KV_ + kv], a);
    sgate[tx] = 2.0f / (1.0f + __expf(-a));
  }
  __syncthreads();
#pragma unroll
  for (int i = 0; i < 16; ++i) {
    const int tr = ty + 4 * i;
    const int row = b * T_ + t0 + tr;
    float gt = sgate[tr];
    float v = bf2f(qkvb[(size_t)row * 1536 + 1280 + kv * 64 + tx]);
    v = fmaf(gt, ve[(size_t)row * (KV_ * D_) + kv * 64 + tx], v);
    tile[tr][tx] = v;
  }
  __syncthreads();
#pragma unroll
  for (int i = 0; i < 16; ++i) {
    const int d = ty + 4 * i;
    vT[((size_t)bk * 64 + d) * T_ + t0 + tx] = f2bf(tile[tx][d]);
  }
}

// ---------------- flash attention: QBLK=128, 8 waves; K dbuf, V single ----------------
// R13-proven body/sync (2 drain barriers/tile, two-phase spt[16][40],
// deferred-l, defer-rescale); plain __launch_bounds__(512) -- no spill.
// LDS 34816 B. Proven best: 44.0 us (R16/R20).
__global__ __launch_bounds__(512) void k_attn(const short* __restrict__ qg,
                                              const short* __restrict__ kg,
                                              const short* __restrict__ vg,
                                              short* __restrict__ yb,
                                              const int* __restrict__ winp) {
  const int wsz = *winp;
  const int qt = blockIdx.x, bh = blockIdx.y;
  const int b = bh >> 4, h = bh & 15;
  const int kvh = h >> 2;
  const int tid = threadIdx.x;
  const int wid = tid >> 6, lane = tid & 63;
  const int g = lane >> 4, c = lane & 15;
  const int t0 = qt * 128 + wid * 16;

  __shared__ short sK[2][64 * 64];
  __shared__ short sV[64 * 64];
  __shared__ short spt_all[8][16][40];
  short (*spt)[40] = spt_all[wid];

  const short* qbase = qg + ((size_t)(b * H_ + h) * T_ + t0) * D_;
  const bf16x8 bq0 = *(const bf16x8*)(qbase + c * D_ + g * 8);
  const bf16x8 bq1 = *(const bf16x8*)(qbase + c * D_ + 32 + g * 8);
  const short* kbase = kg + (size_t)(b * KV_ + kvh) * T_ * D_;
  const short* vbase = vg + (size_t)(b * KV_ + kvh) * D_ * T_;

  const int srow0 = tid >> 3;
  const int sq    = ((tid & 7) ^ (srow0 & 7)) * 8;
  const int ldst0 = wid * 512;

  float m = -20000.0f, l = 0.0f;   // l = per-lane partial (reduced in epilogue)
  f32x4 o[4] = {};

  int lo = t0 - wsz + 1; if (lo < 0) lo = 0;
  const int kt_lo_w = lo >> 6;
  const int kt_hi_w = (t0 + 15) >> 6;
  int lou = qt * 128 - wsz + 1; if (lou < 0) lou = 0;
  const int kt_lo_u = lou >> 6;
  const int kt_hi_u = 2 * qt + 1;
  const int qgl = t0 + c;
  const float SC2 = 0.125f * 1.44269504088896340736f;   // scale * log2(e)

  {  // prologue: K tile only (V staged at loop top)
    const short* ksrc = kbase + (size_t)(kt_lo_u * 64 + srow0) * D_ + sq;
    gld_lds16(ksrc, &sK[0][ldst0]);
  }
  __syncthreads();

  int cb = 0;
  for (int kt = kt_lo_u; kt <= kt_hi_u; ++kt) {
    const int kc0 = kt * 64;
    // top staging: V(kt) into sV, K(kt+1) into sK[cb^1]
    {
      const short* vsrc = vbase + (size_t)srow0 * T_ + kc0 + sq;
      gld_lds16(vsrc, &sV[ldst0]);
    }
    if (kt < kt_hi_u) {
      const short* ksrc = kbase + (size_t)((kt + 1) * 64 + srow0) * D_ + sq;
      gld_lds16(ksrc, &sK[cb ^ 1][ldst0]);
    }
    const bool active = (kt >= kt_lo_w && kt <= kt_hi_w);
    unsigned pb[8];
    float fr = 1.0f;
    bool doresc = false;
    if (active) {
      // S^T = K * Q^T from sK[cb] (swizzled reads)
      f32x4 s[4] = {};
#pragma unroll
      for (int cj = 0; cj < 4; ++cj) {
        const int rbase = (cj * 16 + c) * 64;
        const int sw = (c & 7);
        bf16x8 k0 = *(const bf16x8*)&sK[cb][rbase + ((g ^ sw) * 8)];
        bf16x8 k1 = *(const bf16x8*)&sK[cb][rbase + (((4 + g) ^ sw) * 8)];
        s[cj] = __builtin_amdgcn_mfma_f32_16x16x32_bf16(k0, bq0, s[cj], 0, 0, 0);
        s[cj] = __builtin_amdgcn_mfma_f32_16x16x32_bf16(k1, bq1, s[cj], 0, 0, 0);
      }
      // softmax: sentinel mask, max reduce, defer-rescale (THR=8)
      const bool edge = (kt >= kt_hi_w) || (kt <= kt_lo_w + 1);
      float tmax = -3.0e38f;
#pragma unroll
      for (int cj = 0; cj < 4; ++cj)
#pragma unroll
        for (int r = 0; r < 4; ++r) {
          float v = s[cj][r];
          if (edge) {
            int kv = kc0 + cj * 16 + 4 * g + r;
            v = (kv <= qgl && kv > qgl - wsz) ? v : -1.0e9f;
            s[cj][r] = v;
          }
          tmax = fmaxf(tmax, v);
        }
      tmax = fmaxf(tmax, __shfl_xor(tmax, 16));
      tmax = fmaxf(tmax, __shfl_xor(tmax, 32));
      const float tms = tmax * SC2;
      doresc = !__all(tms <= m + 8.0f);
      if (doresc) {
        const float nm = fmaxf(m, tms);
        fr = exp2fast(m - nm);
        m = nm;
        l *= fr;                       // partial-l rescale (fr uniform per q-row)
      }
      const float negm = -m;
      float psum = 0.0f;
#pragma unroll
      for (int cj = 0; cj < 4; ++cj) {
        float p0 = exp2fast(fmaf(s[cj][0], SC2, negm));
        float p1 = exp2fast(fmaf(s[cj][1], SC2, negm));
        float p2 = exp2fast(fmaf(s[cj][2], SC2, negm));
        float p3 = exp2fast(fmaf(s[cj][3], SC2, negm));
        psum += (p0 + p1) + (p2 + p3);
        pb[2 * cj]     = cvtpk(p0, p1);
        pb[2 * cj + 1] = cvtpk(p2, p3);
      }
      l += psum;                       // cross-lane reduce deferred to epilogue
    }
    __syncthreads();   // BARRIER A: drains V(kt) + K(kt+1); all waves done with sK[cb]
    if (active) {
      // ---- ks-phase 0: kv 0..31 ----
      {
        unsigned long long w0 = ((unsigned long long)pb[1] << 32) | pb[0];
        unsigned long long w1 = ((unsigned long long)pb[3] << 32) | pb[2];
        *(unsigned long long*)&spt[c][4 * g]      = w0;
        *(unsigned long long*)&spt[c][16 + 4 * g] = w1;
      }
      if (doresc) {   // O-rescale covers the P-write latency
#pragma unroll
        for (int nd = 0; nd < 4; ++nd)
#pragma unroll
          for (int r = 0; r < 4; ++r) o[nd][r] *= fr;
      }
      asm volatile("s_waitcnt lgkmcnt(0)" ::: "memory");
      bf16x8 bp0 = *(const bf16x8*)&spt[c][8 * g];
#pragma unroll
      for (int nd = 0; nd < 4; ++nd) {
        const int rbase = (nd * 16 + c) * 64;
        bf16x8 bv = *(const bf16x8*)&sV[rbase + ((g ^ (c & 7)) * 8)];
        o[nd] = __builtin_amdgcn_mfma_f32_16x16x32_bf16(bv, bp0, o[nd], 0, 0, 0);
      }
      // ---- ks-phase 1: kv 32..63 (same spt region; fences order read/write) ----
      asm volatile("s_waitcnt lgkmcnt(0)" ::: "memory");
      {
        unsigned long long w0 = ((unsigned long long)pb[5] << 32) | pb[4];
        unsigned long long w1 = ((unsigned long long)pb[7] << 32) | pb[6];
        *(unsigned long long*)&spt[c][4 * g]      = w0;
        *(unsigned long long*)&spt[c][16 + 4 * g] = w1;
      }
      asm volatile("s_waitcnt lgkmcnt(0)" ::: "memory");
      bf16x8 bp1 = *(const bf16x8*)&spt[c][8 * g];
#pragma unroll
      for (int nd = 0; nd < 4; ++nd) {
        const int rbase = (nd * 16 + c) * 64;
        bf16x8 bv = *(const bf16x8*)&sV[rbase + (((4 + g) ^ (c & 7)) * 8)];
        o[nd] = __builtin_amdgcn_mfma_f32_16x16x32_bf16(bv, bp1, o[nd], 0, 0, 0);
      }
    }
    __syncthreads();   // BARRIER B: protect sV and sK[cb] before next tile's staging
    cb ^= 1;
  }
  // epilogue: deferred l reduction, then O^T store
  l += __shfl_xor(l, 16);
  l += __shfl_xor(l, 32);
  const float inv = 1.0f / l;
#pragma unroll
  for (int nd = 0; nd < 4; ++nd) {
    unsigned d0 = cvtpk(o[nd][0] * inv, o[nd][1] * inv);
    unsigned d1 = cvtpk(o[nd][2] * inv, o[nd][3] * inv);
    unsigned long long w = ((unsigned long long)d1 << 32) | d0;
    *(unsigned long long*)(yb + ((size_t)b * T_ + t0 + c) * C_ + h * D_ + nd * 16 + 4 * g) = w;
  }
}

extern "C" void kernel_launch(void* const* d_in, const int* in_sizes, int n_in,
                              void* d_out, int out_size, void* d_ws, size_t ws_size,
                              hipStream_t stream) {
  const float* x    = (const float*)d_in[0];
  const float* ve   = (const float*)d_in[1];
  const float* cosp = (const float*)d_in[2];
  const float* sinp = (const float*)d_in[3];
  const float* Wq   = (const float*)d_in[4];
  const float* Wk   = (const float*)d_in[5];
  const float* Wv   = (const float*)d_in[6];
  const float* Wo   = (const float*)d_in[7];
  const float* Wg   = (const float*)d_in[8];
  const int*   winp = (const int*)d_in[9];
  float* out = (float*)d_out;
  char* ws = (char*)d_ws;

  const size_t MB = 1024 * 1024;
  short* xb    = (short*)(ws);              // 8 MiB : x bf16 (4096x1024)
  short* wT    = (short*)(ws + 8  * MB);    // 3 MiB : [Wq|Wk|Wv]^T bf16
  short* woT   = (short*)(ws + 11 * MB);    // 2 MiB : Wo^T bf16
  short* qkvb  = (short*)(ws + 13 * MB);    // 12 MiB: qkv bf16 (v region used)
  short* qb    = (short*)(ws + 25 * MB);    // 8 MiB : q bf16 (B,H,T,D) pi-layout
  short* kbuf  = (short*)(ws + 33 * MB);    // 2 MiB : k bf16 (B,KV,T,D) pi-layout
  short* vT    = (short*)(ws + 35 * MB);    // 2 MiB : v bf16 (B,KV,D,T)
  short* yb    = (short*)(ws + 37 * MB);    // 8 MiB : attn out bf16 (B,T,C)

  k_prep<<<6656, 256, 0, stream>>>(x, xb, Wq, Wk, Wv, Wo, wT, woT);
  k_gemm_qkv<<<dim3(12, 64), 256, 0, stream>>>(xb, wT, qkvb, qb, kbuf, cosp, sinp);
  k_vtrans<<<dim3(32, 8), dim3(64, 4), 0, stream>>>(qkvb, ve, x, Wg, vT);
  k_attn<<<dim3(16, 32), 512, 0, stream>>>(qb, kbuf, vT, yb, winp);
  k_gemm64<<<dim3(8, 64), 256, 0, stream>>>(yb, woT, out, M_, 1024, 1024);
}

// Round 26
// 91.334 us; speedup vs baseline: 1.0462x; 1.0001x over previous
//
#include <hip/hip_runtime.h>
#include <hip/hip_bf16.h>

#define B_ 2
#define T_ 2048
#define C_ 1024
#define H_ 16
#define KV_ 4
#define D_ 64
#define M_ (B_*T_)   // 4096

typedef __attribute__((ext_vector_type(4))) float f32x4;
typedef __attribute__((ext_vector_type(8))) short bf16x8;

__device__ __forceinline__ float exp2fast(float x) {
  return __builtin_amdgcn_exp2f(x);   // v_exp_f32 (2^x)
}

__device__ __forceinline__ unsigned short f2bfu(float f) {
  unsigned u = __builtin_bit_cast(unsigned, f);
  u += 0x7FFFu + ((u >> 16) & 1u);   // round-to-nearest-even
  return (unsigned short)(u >> 16);
}

__device__ __forceinline__ short f2bf(float f) {
  return (short)f2bfu(f);
}

__device__ __forceinline__ float bf2f(short s) {
  unsigned u = ((unsigned)(unsigned short)s) << 16;
  return __builtin_bit_cast(float, u);
}

// packed 2xbf16 via HW instruction
__device__ __forceinline__ unsigned cvtpk(float a, float b) {
  unsigned r;
  asm("v_cvt_pk_bf16_f32 %0, %1, %2" : "=v"(r) : "v"(a), "v"(b));
  return r;
}

__device__ __forceinline__ void gld_lds16(const void* g, void* l) {
  __builtin_amdgcn_global_load_lds(
      (const __attribute__((address_space(1))) void*)g,
      (__attribute__((address_space(3))) void*)l, 16, 0, 0);
}

// ---------------- merged prep: x cast (blocks 0..4095) + W transposes ----------------
__global__ __launch_bounds__(256) void k_prep(const float* __restrict__ xin,
                                              short* __restrict__ xb,
                                              const float* __restrict__ Wq,
                                              const float* __restrict__ Wk,
                                              const float* __restrict__ Wv,
                                              const float* __restrict__ Wo,
                                              short* __restrict__ wT,
                                              short* __restrict__ woT) {
  __shared__ float tile[32][33];
  const int bid = blockIdx.x;
  const int tid = threadIdx.x;
  if (bid < 4096) {                 // ---- cast path ----
    int i = (bid * 256 + tid) * 4;
    float4 f = *(const float4*)(xin + i);
    short4 s;
    s.x = f2bf(f.x); s.y = f2bf(f.y); s.z = f2bf(f.z); s.w = f2bf(f.w);
    *(short4*)(xb + i) = s;
    return;
  }
  // ---- transpose path ----
  const int tb = bid - 4096;        // 0..2559
  const int bx = tb % 80;
  const int by = tb / 80;           // 0..31
  const int tx = tid & 31, ty = tid >> 5;
  const float* in; short* out; int Ncol, cb;
  if (bx < 32)      { in = Wq; out = wT;                       Ncol = 1024; cb = bx; }
  else if (bx < 40) { in = Wk; out = wT + (size_t)1024 * 1024; Ncol = 256;  cb = bx - 32; }
  else if (bx < 48) { in = Wv; out = wT + (size_t)1280 * 1024; Ncol = 256;  cb = bx - 40; }
  else              { in = Wo; out = woT;                      Ncol = 1024; cb = bx - 48; }
  const int R = 1024;
  int c0 = cb * 32, r0 = by * 32;
#pragma unroll
  for (int i = 0; i < 32; i += 8)
    tile[ty + i][tx] = in[(size_t)(r0 + ty + i) * Ncol + c0 + tx];
  __syncthreads();
#pragma unroll
  for (int i = 0; i < 32; i += 8)
    out[(size_t)(c0 + ty + i) * R + r0 + tx] = f2bf(tile[tx][ty + i]);
}

// ---------------- bf16 GEMM (f32 out): 64x128 tile, BK=128, 4 waves of 32x64 ----------------
// 16-chunk/row XOR swizzle (source chunk ^= row&15; read (kk*4+g)^c). 8 barriers/K-loop.
__global__ __launch_bounds__(256) void k_gemm64(const short* __restrict__ A,
                                                const short* __restrict__ Bt,
                                                float* __restrict__ C,
                                                int M, int N, int K) {
  __shared__ short sA[64 * 128];
  __shared__ short sB[128 * 128];
  const int tid = threadIdx.x;
  const int wid = tid >> 6, lane = tid & 63;
  const int g = lane >> 4, c = lane & 15;
  const int wm = wid >> 1, wn = wid & 1;
  const int m0 = blockIdx.y * 64, n0 = blockIdx.x * 128;
  const int strow = tid >> 4;                       // 0..15 (row within 16-row issue)
  const int scol  = ((tid & 15) ^ strow) * 8;       // pre-swizzled source chunk

  const short* Ag = A + (size_t)(m0 + strow) * K + scol;
  const short* Bg = Bt + (size_t)(n0 + strow) * K + scol;
  const int ldbase = wid * 512;

  f32x4 acc[2][4] = {};

  for (int k0 = 0; k0 < K; k0 += 128) {
#pragma unroll
    for (int i = 0; i < 4; ++i)
      gld_lds16(Ag + (size_t)(i * 16) * K + k0, &sA[i * 2048 + ldbase]);
#pragma unroll
    for (int i = 0; i < 8; ++i)
      gld_lds16(Bg + (size_t)(i * 16) * K + k0, &sB[i * 2048 + ldbase]);
    __syncthreads();
#pragma unroll
    for (int kk = 0; kk < 4; ++kk) {
      bf16x8 af[2], bfr[4];
#pragma unroll
      for (int i = 0; i < 2; ++i)
        af[i] = *(const bf16x8*)&sA[(wm * 32 + i * 16 + c) * 128 + ((kk * 4 + g) ^ c) * 8];
#pragma unroll
      for (int j = 0; j < 4; ++j)
        bfr[j] = *(const bf16x8*)&sB[(wn * 64 + j * 16 + c) * 128 + ((kk * 4 + g) ^ c) * 8];
#pragma unroll
      for (int i = 0; i < 2; ++i)
#pragma unroll
        for (int j = 0; j < 4; ++j)
          acc[i][j] = __builtin_amdgcn_mfma_f32_16x16x32_bf16(af[i], bfr[j], acc[i][j], 0, 0, 0);
    }
    __syncthreads();
  }
#pragma unroll
  for (int i = 0; i < 2; ++i)
#pragma unroll
    for (int j = 0; j < 4; ++j) {
      int row = m0 + wm * 32 + i * 16 + g * 4;
      int col = n0 + wn * 64 + j * 16 + c;
      float* cp = C + (size_t)row * N + col;
#pragma unroll
      for (int r = 0; r < 4; ++r) cp[(size_t)r * N] = acc[i][j][r];
    }
}

// ---------------- fused QKV GEMM: 64x128 tile, BK=128; epilogue does RoPE+RMS ----------------
__global__ __launch_bounds__(256) void k_gemm_qkv(const short* __restrict__ A,
                                                  const short* __restrict__ Bt,
                                                  short* __restrict__ qkvb,
                                                  short* __restrict__ qb,
                                                  short* __restrict__ kbb,
                                                  const float* __restrict__ cosp,
                                                  const float* __restrict__ sinp) {
  __shared__ short sA[64 * 128];
  __shared__ short sB[128 * 128];
  const int N = 1536, K = 1024;
  const int tid = threadIdx.x;
  const int wid = tid >> 6, lane = tid & 63;
  const int g = lane >> 4, c = lane & 15;
  const int wm = wid >> 1, wn = wid & 1;
  const int m0 = blockIdx.y * 64, n0 = blockIdx.x * 128;
  const int strow = tid >> 4;
  const int scol  = ((tid & 15) ^ strow) * 8;

  const short* Ag = A + (size_t)(m0 + strow) * K + scol;
  const short* Bg = Bt + (size_t)(n0 + strow) * K + scol;
  const int ldbase = wid * 512;

  f32x4 acc[2][4] = {};

  for (int k0 = 0; k0 < K; k0 += 128) {
#pragma unroll
    for (int i = 0; i < 4; ++i)
      gld_lds16(Ag + (size_t)(i * 16) * K + k0, &sA[i * 2048 + ldbase]);
#pragma unroll
    for (int i = 0; i < 8; ++i)
      gld_lds16(Bg + (size_t)(i * 16) * K + k0, &sB[i * 2048 + ldbase]);
    __syncthreads();
#pragma unroll
    for (int kk = 0; kk < 4; ++kk) {
      bf16x8 af[2], bfr[4];
#pragma unroll
      for (int i = 0; i < 2; ++i)
        af[i] = *(const bf16x8*)&sA[(wm * 32 + i * 16 + c) * 128 + ((kk * 4 + g) ^ c) * 8];
#pragma unroll
      for (int j = 0; j < 4; ++j)
        bfr[j] = *(const bf16x8*)&sB[(wn * 64 + j * 16 + c) * 128 + ((kk * 4 + g) ^ c) * 8];
#pragma unroll
      for (int i = 0; i < 2; ++i)
#pragma unroll
        for (int j = 0; j < 4; ++j)
          acc[i][j] = __builtin_amdgcn_mfma_f32_16x16x32_bf16(af[i], bfr[j], acc[i][j], 0, 0, 0);
    }
    __syncthreads();
  }

  const int head = blockIdx.x * 2 + wn;          // 0..23
  const int b = m0 >> 11;                        // 64-row blocks never cross batch
  const int tbase = (m0 & (T_ - 1)) + wm * 32;
  if (head < 20) {
    // RoPE + RMS on f32 accum; store pi-permuted (p = c*4 + j) b64 rows
    short* outbase = (head < 16)
        ? qb  + ((size_t)(b * H_ + head) * T_) * D_
        : kbb + ((size_t)(b * KV_ + (head - 16)) * T_) * D_;
#pragma unroll
    for (int i = 0; i < 2; ++i)
#pragma unroll
      for (int r = 0; r < 4; ++r) {
        const int t = tbase + i * 16 + g * 4 + r;
        const float ca = cosp[t * 32 + c],      sa = sinp[t * 32 + c];
        const float cbv = cosp[t * 32 + 16 + c], sbv = sinp[t * 32 + 16 + c];
        const float f0 = acc[i][0][r], f1 = acc[i][1][r];
        const float f2 = acc[i][2][r], f3 = acc[i][3][r];
        const float r0 = f0 * ca + f2 * sa;
        const float r1 = f1 * cbv + f3 * sbv;
        const float r2 = f2 * ca - f0 * sa;
        const float r3 = f3 * cbv - f1 * sbv;
        float ss = (r0 * r0 + r1 * r1) + (r2 * r2 + r3 * r3);
        ss += __shfl_xor(ss, 1);
        ss += __shfl_xor(ss, 2);
        ss += __shfl_xor(ss, 4);
        ss += __shfl_xor(ss, 8);
        const float sc = rsqrtf(ss * (1.0f / 64.0f) + 1.1920929e-07f);
        unsigned w0 = cvtpk(r0 * sc, r1 * sc);
        unsigned w1 = cvtpk(r2 * sc, r3 * sc);
        unsigned long long w = ((unsigned long long)w1 << 32) | w0;
        *(unsigned long long*)(outbase + (size_t)t * D_ + c * 4) = w;
      }
  } else {
    // raw v -> qkvb (natural layout)
#pragma unroll
    for (int i = 0; i < 2; ++i)
#pragma unroll
      for (int j = 0; j < 4; ++j) {
        int row = m0 + wm * 32 + i * 16 + g * 4;
        int col = n0 + wn * 64 + j * 16 + c;
        short* cp = qkvb + (size_t)row * N + col;
#pragma unroll
        for (int r = 0; r < 4; ++r) cp[(size_t)r * N] = f2bf(acc[i][j][r]);
      }
  }
}

// ---------------- gate + v = qkv.v + gate*ve, transposed to (B,KV,D,T) ----------------
__global__ __launch_bounds__(256) void k_vtrans(const short* __restrict__ qkvb,
                                                const float* __restrict__ ve,
                                                const float* __restrict__ x,
                                                const float* __restrict__ Wg,
                                                short* __restrict__ vT) {
  const int t0 = blockIdx.x * 64;
  const int bk = blockIdx.y;             // b*KV + kv
  const int b = bk >> 2, kv = bk & 3;
  const int tx = threadIdx.x;            // 0..63
  const int ty = threadIdx.y;            // 0..3
  __shared__ float tile[64][65];
  __shared__ float sgate[64];
  if (ty == 0) {
    const int row = b * T_ + t0 + tx;
    const float* xr = x + (size_t)row * C_;
    float a = 0.0f;
#pragma unroll 8
    for (int kk = 0; kk < 32; ++kk) a = fmaf(xr[kk], Wg[kk * KV_ + kv], a);
    sgate[tx] = 2.0f / (1.0f + __expf(-a));
  }
  __syncthreads();
#pragma unroll
  for (int i = 0; i < 16; ++i) {
    const int tr = ty + 4 * i;
    const int row = b * T_ + t0 + tr;
    float gt = sgate[tr];
    float v = bf2f(qkvb[(size_t)row * 1536 + 1280 + kv * 64 + tx]);
    v = fmaf(gt, ve[(size_t)row * (KV_ * D_) + kv * 64 + tx], v);
    tile[tr][tx] = v;
  }
  __syncthreads();
#pragma unroll
  for (int i = 0; i < 16; ++i) {
    const int d = ty + 4 * i;
    vT[((size_t)bk * 64 + d) * T_ + t0 + tx] = f2bf(tile[tx][d]);
  }
}

// ---------------- flash attention: QBLK=128, 8 waves, K/V double-buffered ----------------
// R12-body (bit-stable absmax 0.015625 across R8/R10/R11/R15, post-timing
// validated each time): all-dbuf staging at tile top, single-phase padded
// spt[16][72] P round-trip, ONE drain barrier per tile. grid (x=qt, y=bh).
__global__ __launch_bounds__(512, 6) void k_attn(const short* __restrict__ qg,
                                                 const short* __restrict__ kg,
                                                 const short* __restrict__ vg,
                                                 short* __restrict__ yb,
                                                 const int* __restrict__ winp) {
  const int wsz = *winp;
  const int qt = blockIdx.x, bh = blockIdx.y;
  const int b = bh >> 4, h = bh & 15;
  const int kvh = h >> 2;
  const int tid = threadIdx.x;
  const int wid = tid >> 6, lane = tid & 63;
  const int g = lane >> 4, c = lane & 15;
  const int t0 = qt * 128 + wid * 16;

  __shared__ short sK[2][64 * 64];
  __shared__ short sV[2][64 * 64];
  __shared__ short spt_all[8][16][72];
  short (*spt)[72] = spt_all[wid];

  const short* qbase = qg + ((size_t)(b * H_ + h) * T_ + t0) * D_;
  const bf16x8 bq0 = *(const bf16x8*)(qbase + c * D_ + g * 8);
  const bf16x8 bq1 = *(const bf16x8*)(qbase + c * D_ + 32 + g * 8);
  const short* kbase = kg + (size_t)(b * KV_ + kvh) * T_ * D_;
  const short* vbase = vg + (size_t)(b * KV_ + kvh) * D_ * T_;

  const int srow0 = tid >> 3;
  const int sq    = ((tid & 7) ^ (srow0 & 7)) * 8;
  const int ldst0 = wid * 512;

  float m = -20000.0f, l = 0.0f;
  f32x4 o[4] = {};

  int lo = t0 - wsz + 1; if (lo < 0) lo = 0;
  const int kt_lo_w = lo >> 6;
  const int kt_hi_w = (t0 + 15) >> 6;
  int lou = qt * 128 - wsz + 1; if (lou < 0) lou = 0;
  const int kt_lo_u = lou >> 6;
  const int kt_hi_u = 2 * qt + 1;
  const int qgl = t0 + c;
  const float SC2 = 0.125f * 1.44269504088896340736f;   // scale * log2(e)

  {
    const short* ksrc = kbase + (size_t)(kt_lo_u * 64 + srow0) * D_ + sq;
    gld_lds16(ksrc, &sK[0][ldst0]);
    const short* vsrc = vbase + (size_t)srow0 * T_ + kt_lo_u * 64 + sq;
    gld_lds16(vsrc, &sV[0][ldst0]);
  }
  __syncthreads();

  int cb = 0;
  for (int kt = kt_lo_u; kt <= kt_hi_u; ++kt) {
    const int kc0 = kt * 64;
    if (kt < kt_hi_u) {
      const short* ksrc = kbase + (size_t)((kt + 1) * 64 + srow0) * D_ + sq;
      gld_lds16(ksrc, &sK[cb ^ 1][ldst0]);
      const short* vsrc = vbase + (size_t)srow0 * T_ + (kt + 1) * 64 + sq;
      gld_lds16(vsrc, &sV[cb ^ 1][ldst0]);
    }
    if (kt >= kt_lo_w && kt <= kt_hi_w) {
      // S^T = K * Q^T from sK[cb] (swizzled reads)
      f32x4 s[4] = {};
#pragma unroll
      for (int cj = 0; cj < 4; ++cj) {
        const int rbase = (cj * 16 + c) * 64;
        const int sw = (c & 7);
        bf16x8 k0 = *(const bf16x8*)&sK[cb][rbase + ((g ^ sw) * 8)];
        bf16x8 k1 = *(const bf16x8*)&sK[cb][rbase + (((4 + g) ^ sw) * 8)];
        s[cj] = __builtin_amdgcn_mfma_f32_16x16x32_bf16(k0, bq0, s[cj], 0, 0, 0);
        s[cj] = __builtin_amdgcn_mfma_f32_16x16x32_bf16(k1, bq1, s[cj], 0, 0, 0);
      }
      // softmax on raw scores: sentinel mask, max, deferred rescale (THR=8)
      const bool edge = (kt >= kt_hi_w) || (kt <= kt_lo_w + 1);
      float tmax = -3.0e38f;
#pragma unroll
      for (int cj = 0; cj < 4; ++cj)
#pragma unroll
        for (int r = 0; r < 4; ++r) {
          float v = s[cj][r];
          if (edge) {
            int kv = kc0 + cj * 16 + 4 * g + r;
            v = (kv <= qgl && kv > qgl - wsz) ? v : -1.0e9f;
            s[cj][r] = v;
          }
          tmax = fmaxf(tmax, v);
        }
      tmax = fmaxf(tmax, __shfl_xor(tmax, 16));
      tmax = fmaxf(tmax, __shfl_xor(tmax, 32));
      const float tms = tmax * SC2;
      if (!__all(tms <= m + 8.0f)) {
        const float nm = fmaxf(m, tms);
        const float fr = exp2fast(m - nm);
        m = nm;
        l *= fr;
#pragma unroll
        for (int nd = 0; nd < 4; ++nd)
#pragma unroll
          for (int r = 0; r < 4; ++r) o[nd][r] *= fr;
      }
      const float negm = -m;
      float psum = 0.0f;
      unsigned pb[8];
#pragma unroll
      for (int cj = 0; cj < 4; ++cj) {
        float p0 = exp2fast(fmaf(s[cj][0], SC2, negm));
        float p1 = exp2fast(fmaf(s[cj][1], SC2, negm));
        float p2 = exp2fast(fmaf(s[cj][2], SC2, negm));
        float p3 = exp2fast(fmaf(s[cj][3], SC2, negm));
        psum += (p0 + p1) + (p2 + p3);
        pb[2 * cj]     = cvtpk(p0, p1);
        pb[2 * cj + 1] = cvtpk(p2, p3);
      }
      psum += __shfl_xor(psum, 16);
      psum += __shfl_xor(psum, 32);
      l += psum;
      // P^T regs -> per-wave LDS (packed b64), re-read as B-operand frags
#pragma unroll
      for (int cj = 0; cj < 4; ++cj) {
        unsigned long long w = ((unsigned long long)pb[2 * cj + 1] << 32) | pb[2 * cj];
        *(unsigned long long*)&spt[c][cj * 16 + 4 * g] = w;
      }
      asm volatile("s_waitcnt lgkmcnt(0)" ::: "memory");
#pragma unroll
      for (int ks = 0; ks < 2; ++ks) {
        bf16x8 bp = *(const bf16x8*)&spt[c][ks * 32 + g * 8];
#pragma unroll
        for (int nd = 0; nd < 4; ++nd) {
          const int rbase = (nd * 16 + c) * 64;
          bf16x8 bv = *(const bf16x8*)&sV[cb][rbase + (((ks * 4 + g) ^ (c & 7)) * 8)];
          o[nd] = __builtin_amdgcn_mfma_f32_16x16x32_bf16(bv, bp, o[nd], 0, 0, 0);
        }
      }
    }
    __syncthreads();   // single barrier: drains prefetch, protects both buffers
    cb ^= 1;
  }
  // O^T epilogue
  const float inv = 1.0f / l;
#pragma unroll
  for (int nd = 0; nd < 4; ++nd) {
    unsigned d0 = cvtpk(o[nd][0] * inv, o[nd][1] * inv);
    unsigned d1 = cvtpk(o[nd][2] * inv, o[nd][3] * inv);
    unsigned long long w = ((unsigned long long)d1 << 32) | d0;
    *(unsigned long long*)(yb + ((size_t)b * T_ + t0 + c) * C_ + h * D_ + nd * 16 + 4 * g) = w;
  }
}

extern "C" void kernel_launch(void* const* d_in, const int* in_sizes, int n_in,
                              void* d_out, int out_size, void* d_ws, size_t ws_size,
                              hipStream_t stream) {
  const float* x    = (const float*)d_in[0];
  const float* ve   = (const float*)d_in[1];
  const float* cosp = (const float*)d_in[2];
  const float* sinp = (const float*)d_in[3];
  const float* Wq   = (const float*)d_in[4];
  const float* Wk   = (const float*)d_in[5];
  const float* Wv   = (const float*)d_in[6];
  const float* Wo   = (const float*)d_in[7];
  const float* Wg   = (const float*)d_in[8];
  const int*   winp = (const int*)d_in[9];
  float* out = (float*)d_out;
  char* ws = (char*)d_ws;

  const size_t MB = 1024 * 1024;
  short* xb    = (short*)(ws);              // 8 MiB : x bf16 (4096x1024)
  short* wT    = (short*)(ws + 8  * MB);    // 3 MiB : [Wq|Wk|Wv]^T bf16
  short* woT   = (short*)(ws + 11 * MB);    // 2 MiB : Wo^T bf16
  short* qkvb  = (short*)(ws + 13 * MB);    // 12 MiB: qkv bf16 (v region used)
  short* qb    = (short*)(ws + 25 * MB);    // 8 MiB : q bf16 (B,H,T,D) pi-layout
  short* kbuf  = (short*)(ws + 33 * MB);    // 2 MiB : k bf16 (B,KV,T,D) pi-layout
  short* vT    = (short*)(ws + 35 * MB);    // 2 MiB : v bf16 (B,KV,D,T)
  short* yb    = (short*)(ws + 37 * MB);    // 8 MiB : attn out bf16 (B,T,C)

  k_prep<<<6656, 256, 0, stream>>>(x, xb, Wq, Wk, Wv, Wo, wT, woT);
  k_gemm_qkv<<<dim3(12, 64), 256, 0, stream>>>(xb, wT, qkvb, qb, kbuf, cosp, sinp);
  k_vtrans<<<dim3(32, 8), dim3(64, 4), 0, stream>>>(qkvb, ve, x, Wg, vT);
  k_attn<<<dim3(16, 32), 512, 0, stream>>>(qb, kbuf, vT, yb, winp);
  k_gemm64<<<dim3(8, 64), 256, 0, stream>>>(yb, woT, out, M_, 1024, 1024);
}